// Round 3
// baseline (413.907 us; speedup 1.0000x reference)
//
#include <hip/hip_runtime.h>
#include <math.h>

// ---------------- problem constants ----------------
#define NT 512      // N_TARGET
#define NF 1024     // N_FEAT
#define NFUNC 32
#define BATCHSZ 16

// output layout (float elements, concatenated in return order)
constexpr int O_MEM  = 0;          // 16384*512
constexpr int O_TMEM = 8388608;    // 16384 (written as float)
constexpr int O_FEAT = 8404992;    // 16384*1024
constexpr int O_ARE  = 25182208;   // 32*512
constexpr int O_AIM  = 25198592;
constexpr int O_FREQ = 25214976;   // 32
constexpr int O_RP   = 25215008;   // 1536*512
constexpr int O_BIAS = 26001440;   // 512
constexpr int O_FM   = 26001952;   // 1024
constexpr int O_AGR  = 26002976;   // 32*512
constexpr int O_AGI  = 26019360;
constexpr int O_FGR  = 26035744;   // 32
constexpr int O_RPG  = 26035776;   // 1536*512

// ws layout (floats)
constexpr int W_LR    = 0;
constexpr int W_ANORM = 2;   // [2] per-batch
constexpr int W_RNORM = 4;   // [2]
constexpr int W_GFR   = 8;   // [2*32]
constexpr int W_TB    = 72;  // [16]
constexpr int W_C     = 96;    // [16*32]
constexpr int W_S     = 608;   // [16*32]
constexpr int W_CATZ  = 1120;  // [16*512]
constexpr int W_CATX  = 9312;  // [16*1024]
constexpr int W_GR    = 25696; // [16*512]
constexpr int W_G     = 33888; // [16*512]
constexpr int W_AGRE  = 42080; // [32*512]
constexpr int W_AGIM  = 58464; // [32*512]
constexpr int W_RPART = 74848; // [16*8192] split-K partials

constexpr float MM_LR = 0.03f;
constexpr float AMP_DECAY = 0.01f;
constexpr float MOM = 0.85f;
constexpr float INV_SQRT_NF = 0.17677669529663687f; // 1/sqrt(32)
constexpr float TWO_PI = 6.283185307179586f;

constexpr int NCOPY = 256;               // copy-helper blocks per kernel
constexpr long long U_TOTAL = 6295552LL; // float4 units: mem 2097152 + feat 4194304 + tmem 4096

__device__ __forceinline__ float sgnf(float x) {
    return (x > 0.f) ? 1.f : ((x < 0.f) ? -1.f : 0.f);
}

__device__ __forceinline__ float wave_reduce(float v) {
#pragma unroll
    for (int o = 32; o > 0; o >>= 1) v += __shfl_down(v, o, 64);
    return v; // lane 0 holds sum
}

// ------------- background copy: slice [cbase, cbase+ccnt) of U_TOTAL -------------
__device__ __forceinline__ void copy_role(int rb, int cbase, int ccnt,
    const int* __restrict__ tptr, const int* __restrict__ dsptr,
    const float* __restrict__ x, const float* __restrict__ z,
    const float* __restrict__ memory, const int* __restrict__ t_memory,
    const float* __restrict__ feat_memory, float* __restrict__ out)
{
    const int dsv = *dsptr;
    const int tt  = *tptr;
    const int nthr = NCOPY * 256;
    for (int q = rb * 256 + (int)threadIdx.x; q * 4 < ccnt; q += nthr) {
#pragma unroll
        for (int w = 0; w < 4; ++w) {
            int rel = q * 4 + w;
            if (rel >= ccnt) break;
            int u = cbase + rel;
            if (u < 2097152) {               // memory (row ds <- z)
                int row = u >> 7;
                float4 v = (row == dsv) ? ((const float4*)z)[u & 127]
                                        : ((const float4*)memory)[u];
                ((float4*)(out + O_MEM))[u] = v;
            } else if (u < 6291456) {        // feat_memory (row ds <- x)
                int f = u - 2097152;
                int row = f >> 8;
                float4 v = (row == dsv) ? ((const float4*)x)[f & 255]
                                        : ((const float4*)feat_memory)[f];
                ((float4*)(out + O_FEAT))[f] = v;
            } else {                          // t_memory -> float (row ds <- t)
                int f = u - 6291456;
                int4 iv = ((const int4*)t_memory)[f];
                int e = f * 4;
                float* o = out + O_TMEM + e;
                o[0] = (e + 0 == dsv) ? (float)tt : (float)iv.x;
                o[1] = (e + 1 == dsv) ? (float)tt : (float)iv.y;
                o[2] = (e + 2 == dsv) ? (float)tt : (float)iv.z;
                o[3] = (e + 3 == dsv) ? (float)tt : (float)iv.w;
            }
        }
    }
}

#define COPY_ARGS const int* __restrict__ tptr, const int* __restrict__ dsptr,            \
                  const float* __restrict__ x, const float* __restrict__ z,               \
                  const float* __restrict__ memory, const int* __restrict__ t_memory,     \
                  const float* __restrict__ feat_memory, int cbase, int ccnt
#define COPY_PASS tptr, dsptr, x, z, memory, t_memory, feat_memory

// ======== K1: fused cat + split-K matmul partials. block=(i, s-chunk) ========
__global__ __launch_bounds__(256) void k_fwd_ab(int b, const int* __restrict__ ts,
    const float* __restrict__ cf,
    const float* __restrict__ are_src, const float* __restrict__ aim_src,
    const float* __restrict__ fq_src, const float* __restrict__ fm_in,
    const float* __restrict__ rp_src,
    float* __restrict__ out, float* __restrict__ ws, COPY_ARGS)
{
    const int bb = blockIdx.x, tid = threadIdx.x;
    if (bb >= 256) { copy_role(bb - 256, cbase, ccnt, COPY_PASS, out); return; }
    const int i = bb >> 4, s = bb & 15;
    __shared__ float c_l[32], s_l[32], cat[96];
    const int dsv = *dsptr;
    const int bi = ts[b * BATCHSZ + i];
    if (tid < 32) {
        float f  = fq_src[tid];
        float th = tanhf(f);
        float u  = cf[tid] + 2.f * th;
        float sg = 1.f / (1.f + expf(-u));
        float fr = 0.5f * sg;
        float tb = (bi == dsv) ? (float)(*tptr) : (float)t_memory[bi];
        float ph = TWO_PI * tb * fr;
        float cv = cosf(ph), sv = sinf(ph);
        c_l[tid] = cv; s_l[tid] = sv;
        if (s == 0) {
            ws[W_C + i*32 + tid] = cv; ws[W_S + i*32 + tid] = sv;
            if (tid == 0) ws[W_TB + i] = tb;
        }
    }
    if (bb == 0) {  // per-batch accumulator init
        if (tid == 64) ws[W_ANORM + b] = 0.f;
        if (tid == 65) ws[W_RNORM + b] = 0.f;
        if (tid == 66 && b == 0) ws[W_LR] = (float)pow(0.977, (double)(dsv + 1));
        if (tid >= 96 && tid < 128) ws[W_GFR + b*32 + tid - 96] = 0.f;
    }
    __syncthreads();
    if (tid < 96) {                     // compute this block's 96-elem cat slice
        int p = s * 96 + tid;
        float cv;
        if (p < NF) {
            const float nn = (float)(dsv + 1), dd = (float)(dsv + 2);
            float fmv = (fm_in[p] * nn + x[p]) / dd;
            float xv  = (bi == dsv) ? x[p] : feat_memory[bi*NF + p];
            cv = xv - fmv;
            ws[W_CATX + i*NF + p] = cv;
        } else {
            int q = p - NF;
            float acc = 0.f;
#pragma unroll
            for (int k = 0; k < 32; ++k)
                acc += c_l[k] * are_src[k*NT + q] - s_l[k] * aim_src[k*NT + q];
            cv = acc * INV_SQRT_NF;     // z_ - bias
            ws[W_CATZ + i*NT + q] = cv;
        }
        cat[tid] = cv;
    }
    __syncthreads();
    const int j = tid;
    const float* rpb = rp_src + (size_t)s * 96 * NT;
    float a0 = 0.f, a1 = 0.f, b0 = 0.f, b1 = 0.f;
#pragma unroll 8
    for (int p = 0; p < 96; p += 2) {
        float c0 = cat[p], c1 = cat[p + 1];
        a0 += c0 * rpb[p*NT + j];
        a1 += c0 * rpb[p*NT + j + 256];
        b0 += c1 * rpb[(p+1)*NT + j];
        b1 += c1 * rpb[(p+1)*NT + j + 256];
    }
    ws[W_RPART + s*8192 + i*NT + j]       = a0 + b0;
    ws[W_RPART + s*8192 + i*NT + j + 256] = a1 + b1;
}

// ======== K2: epilogue — r, g_r, FULL G (direct+residual). block=(i, j-half) ========
__global__ __launch_bounds__(256) void k_eplg2(int b, const int* __restrict__ ts,
    const float* __restrict__ bias_in, const float* __restrict__ fm_in,
    const float* __restrict__ rp_src,
    float* __restrict__ out, float* __restrict__ ws, COPY_ARGS)
{
    const int bb = blockIdx.x, tid = threadIdx.x;
    if (bb >= 32) { copy_role(bb - 32, cbase, ccnt, COPY_PASS, out); return; }
    const int i = bb >> 1, half = bb & 1;
    __shared__ float g_sh[NT], d_sh[NT];
    const int dsv = *dsptr;
    const int bi = ts[b * BATCHSZ + i];
    const float nn = (float)(dsv + 1), dd = (float)(dsv + 2);
#pragma unroll
    for (int ll = 0; ll < 2; ++ll) {
        int l = tid + ll * 256;
        float r = 0.f;
#pragma unroll
        for (int s = 0; s < 16; ++s) r += ws[W_RPART + s*8192 + i*NT + l];
        float bn = (bias_in[l] * nn + z[l]) / dd;
        float zj = ws[W_CATZ + i*NT + l] + bn;
        float zb = (bi == dsv) ? z[l] : memory[bi*NT + l];
        float s1 = sgnf(zj - zb);
        float ar = fabsf(r) + 1.f;
        float z2 = zj + r / ar;
        float g  = sgnf(z2 - zb) * (MM_LR / 16.f) / (ar * ar);
        g_sh[l] = g; d_sh[l] = s1 * (1.f / 16.f);
        ws[W_GR + i*NT + l] = g;   // both half-blocks write bit-identical values
        if (b == 0 && bb == 0) out[O_BIAS + l] = bn;
    }
    if (b == 0 && bb < 2) {        // fm_new (blocks 0,1 cover 1024)
#pragma unroll
        for (int ll = 0; ll < 2; ++ll) {
            int p = half * 512 + tid + ll * 256;
            out[O_FM + p] = (fm_in[p] * nn + x[p]) / dd;
        }
    }
    __syncthreads();
    const int w = tid >> 6, lane = tid & 63;
    const int jbase = half * 256 + w * 64;
    for (int jj = 0; jj < 64; ++jj) {
        int j = jbase + jj;
        const float* rrow = rp_src + (size_t)(NF + j) * NT;
        float acc = 0.f;
#pragma unroll
        for (int l = lane; l < NT; l += 64) acc += g_sh[l] * rrow[l];
        acc = wave_reduce(acc);
        if (lane == 0) ws[W_G + i*NT + j] = d_sh[j] + acc;
    }
}

// ======== K3: all norms — amp grads+anorm [0,64) | gfr [64,192) | rg+rnorm [192,3264) ========
__global__ __launch_bounds__(256) void k_norms(int b,
    const float* __restrict__ are_src, const float* __restrict__ aim_src,
    float* __restrict__ out, float* __restrict__ ws, COPY_ARGS)
{
    __shared__ float red[4];
    const int bb = blockIdx.x, tid = threadIdx.x;
    if (bb >= 3264) { copy_role(bb - 3264, cbase, ccnt, COPY_PASS, out); return; }
    if (bb < 64) {
        int e = bb*256 + tid;
        int k = e >> 9;
        float gre = 0.f, gim = 0.f;
#pragma unroll
        for (int i2 = 0; i2 < 16; ++i2) {
            float G = ws[W_G + i2*NT + (e & 511)];
            gre += G * ws[W_C + i2*32 + k];
            gim += G * ws[W_S + i2*32 + k];
        }
        float re = are_src[e], im = aim_src[e];
        float aa = sqrtf(re*re + im*im);
        float dec = AMP_DECAY / (2.f * aa * sqrtf(aa));
        float agr =  gre * INV_SQRT_NF + re * dec;
        float agi = -gim * INV_SQRT_NF + im * dec;
        ws[W_AGRE + e] = agr;
        ws[W_AGIM + e] = agi;
        float v = wave_reduce(agr*agr + agi*agi);
        if ((tid & 63) == 0) red[tid >> 6] = v;
        __syncthreads();
        if (tid == 0) atomicAdd(&ws[W_ANORM + b], red[0]+red[1]+red[2]+red[3]);
    } else if (bb < 192) {
        int wid = tid >> 6, lane = tid & 63;
        int pair = (bb - 64)*4 + wid;      // 512 = 16 i x 32 k
        int i = pair >> 5, k = pair & 31;
        float ck = ws[W_C + i*32 + k], sk = ws[W_S + i*32 + k];
        float acc = 0.f;
#pragma unroll
        for (int j = lane; j < NT; j += 64)
            acc += ws[W_G + i*NT + j] * (-sk * are_src[k*NT + j] - ck * aim_src[k*NT + j]);
        acc = wave_reduce(acc);
        if (lane == 0)
            atomicAdd(&ws[W_GFR + b*32 + k], acc * TWO_PI * ws[W_TB + i] * INV_SQRT_NF);
    } else {
        int e = (bb - 192)*256 + tid;
        int p = e >> 9, j = e & 511;
        float rg = 0.f;
#pragma unroll
        for (int i2 = 0; i2 < 16; ++i2) {
            float cat = (p < NF) ? ws[W_CATX + i2*NF + p]
                                 : ws[W_CATZ + i2*NT + (p - NF)];
            rg += cat * ws[W_GR + i2*NT + j];
        }
        float v = wave_reduce(rg * rg);
        if ((tid & 63) == 0) red[tid >> 6] = v;
        __syncthreads();
        if (tid == 0) atomicAdd(&ws[W_RNORM + b], red[0]+red[1]+red[2]+red[3]);
    }
}

// ======== K4: parameter updates ========
__global__ __launch_bounds__(256) void k_upd(int b, const float* __restrict__ cf,
    const float* __restrict__ are_src, const float* __restrict__ aim_src,
    const float* __restrict__ agr_src, const float* __restrict__ agi_src,
    const float* __restrict__ fq_src,  const float* __restrict__ fgr_src,
    const float* __restrict__ rp_src,  const float* __restrict__ rpg_src,
    float* __restrict__ out, float* __restrict__ ws, COPY_ARGS)
{
    const int bb = blockIdx.x, tid = threadIdx.x;
    if (bb >= 3137) { copy_role(bb - 3137, cbase, ccnt, COPY_PASS, out); return; }
    const float lr = ws[W_LR];
    if (bb < 64) {
        int e = bb*256 + tid;
        float anorm = sqrtf(ws[W_ANORM + b]) + 1.f;
        float mr = agr_src[e]*MOM + ws[W_AGRE + e]/anorm;
        out[O_AGR + e] = mr; out[O_ARE + e] = are_src[e] - mr*lr;
        float mi = agi_src[e]*MOM + ws[W_AGIM + e]/anorm;
        out[O_AGI + e] = mi; out[O_AIM + e] = aim_src[e] - mi*lr;
    } else if (bb == 64) {
        if (tid < 64) {
            float fg = 0.f, th = 0.f;
            if (tid < 32) {
                float f = fq_src[tid];
                th = tanhf(f);
                float u  = cf[tid] + 2.f*th;
                float sg = 1.f / (1.f + expf(-u));
                fg = ws[W_GFR + b*32 + tid] * sg*(1.f-sg)*(1.f-th*th);
            }
            float t2 = fg*fg;
#pragma unroll
            for (int o = 32; o > 0; o >>= 1) t2 += __shfl_down(t2, o, 64);
            float tot = __shfl(t2, 0, 64);
            if (tid < 32) {
                float fnorm = sqrtf(tot) + 1.f;
                float m = fgr_src[tid]*MOM + fg/fnorm;
                out[O_FGR + tid] = m;
                out[O_FREQ + tid] = fq_src[tid] - m*lr;
            }
        }
    } else {
        int e = (bb - 65)*256 + tid;
        int p = e >> 9, j = e & 511;
        float rg = 0.f;
#pragma unroll
        for (int i2 = 0; i2 < 16; ++i2) {
            float cat = (p < NF) ? ws[W_CATX + i2*NF + p]
                                 : ws[W_CATZ + i2*NT + (p - NF)];
            rg += cat * ws[W_GR + i2*NT + j];   // same order as k_norms -> identical fp
        }
        float rnorm = sqrtf(ws[W_RNORM + b]) + 1.f;
        float m = rpg_src[e]*MOM + rg/rnorm;
        out[O_RPG + e] = m; out[O_RP + e] = rp_src[e] - m*lr;
    }
}

extern "C" void kernel_launch(void* const* d_in, const int* in_sizes, int n_in,
                              void* d_out, int out_size, void* d_ws, size_t ws_size,
                              hipStream_t stream)
{
    const int*   t            = (const int*)d_in[0];
    const int*   dsp          = (const int*)d_in[1];
    const int*   ts           = (const int*)d_in[2];
    const float* x            = (const float*)d_in[3];
    const float* z            = (const float*)d_in[4];
    const float* memory       = (const float*)d_in[5];
    const int*   t_memory     = (const int*)d_in[6];
    const float* feat_memory  = (const float*)d_in[7];
    const float* amp_re       = (const float*)d_in[8];
    const float* amp_im       = (const float*)d_in[9];
    const float* freq         = (const float*)d_in[10];
    const float* cf           = (const float*)d_in[11];
    const float* res_proj     = (const float*)d_in[12];
    const float* feat_mean    = (const float*)d_in[13];
    const float* bias         = (const float*)d_in[14];
    const float* amp_grad_re  = (const float*)d_in[15];
    const float* amp_grad_im  = (const float*)d_in[16];
    const float* freq_grad    = (const float*)d_in[17];
    const float* res_proj_grad= (const float*)d_in[18];
    float* out = (float*)d_out;
    float* ws  = (float*)d_ws;

    const float* ARE[2] = { amp_re,        out + O_ARE };
    const float* AIM[2] = { amp_im,        out + O_AIM };
    const float* AGR[2] = { amp_grad_re,   out + O_AGR };
    const float* AGI[2] = { amp_grad_im,   out + O_AGI };
    const float* FQ [2] = { freq,          out + O_FREQ };
    const float* FGR[2] = { freq_grad,     out + O_FGR };
    const float* RP [2] = { res_proj,      out + O_RP };
    const float* RPG[2] = { res_proj_grad, out + O_RPG };

    // 8 equal copy slices (U_TOTAL = 8 * 786944)
    const int per = 786944;
    int base = 0;
    auto nxt = [&](int& cb, int& cc) { cb = base; cc = per; base += cc; };
    int cb, cc;
    for (int b = 0; b < 2; ++b) {
        nxt(cb, cc);
        k_fwd_ab<<<256 + NCOPY, 256, 0, stream>>>(b, ts, cf, ARE[b], AIM[b], FQ[b],
            feat_mean, RP[b], out, ws, t, dsp, x, z, memory, t_memory, feat_memory, cb, cc);
        nxt(cb, cc);
        k_eplg2<<<32 + NCOPY, 256, 0, stream>>>(b, ts, bias, feat_mean, RP[b], out, ws,
            t, dsp, x, z, memory, t_memory, feat_memory, cb, cc);
        nxt(cb, cc);
        k_norms<<<3264 + NCOPY, 256, 0, stream>>>(b, ARE[b], AIM[b], out, ws,
            t, dsp, x, z, memory, t_memory, feat_memory, cb, cc);
        nxt(cb, cc);
        k_upd<<<3137 + NCOPY, 256, 0, stream>>>(b, cf, ARE[b], AIM[b], AGR[b], AGI[b],
            FQ[b], FGR[b], RP[b], RPG[b], out, ws,
            t, dsp, x, z, memory, t_memory, feat_memory, cb, cc);
    }
}

// Round 4
// 360.713 us; speedup vs baseline: 1.1475x; 1.1475x over previous
//
#include <hip/hip_runtime.h>
#include <math.h>

// ---------------- problem constants ----------------
#define NT 512      // N_TARGET
#define NF 1024     // N_FEAT
#define NFUNC 32
#define BATCHSZ 16

// output layout (float elements, concatenated in return order)
constexpr int O_MEM  = 0;          // 16384*512
constexpr int O_TMEM = 8388608;    // 16384 (written as float)
constexpr int O_FEAT = 8404992;    // 16384*1024
constexpr int O_ARE  = 25182208;   // 32*512
constexpr int O_AIM  = 25198592;
constexpr int O_FREQ = 25214976;   // 32
constexpr int O_RP   = 25215008;   // 1536*512
constexpr int O_BIAS = 26001440;   // 512
constexpr int O_FM   = 26001952;   // 1024
constexpr int O_AGR  = 26002976;   // 32*512
constexpr int O_AGI  = 26019360;
constexpr int O_FGR  = 26035744;   // 32
constexpr int O_RPG  = 26035776;   // 1536*512

// ws layout (floats)
constexpr int W_LR    = 0;
constexpr int W_ANORM = 2;   // [2] per-batch
constexpr int W_RNORM = 4;   // [2]
constexpr int W_GFR   = 8;   // [2*32]
constexpr int W_TB    = 72;  // [16]
constexpr int W_C     = 96;    // [16*32]
constexpr int W_S     = 608;   // [16*32]
constexpr int W_CATZ  = 1120;  // [16*512]
constexpr int W_CATX  = 9312;  // [16*1024]
constexpr int W_GR    = 25696; // [16*512]
constexpr int W_G     = 33888; // [16*512]
constexpr int W_AGRE  = 42080; // [32*512]
constexpr int W_AGIM  = 58464; // [32*512]
constexpr int W_RPART = 74848; // [16*8192] split-K partials

constexpr float MM_LR = 0.03f;
constexpr float AMP_DECAY = 0.01f;
constexpr float MOM = 0.85f;
constexpr float INV_SQRT_NF = 0.17677669529663687f; // 1/sqrt(32)
constexpr float TWO_PI = 6.283185307179586f;

constexpr int NCOPY = 256;               // copy-helper blocks per kernel
constexpr long long U_TOTAL = 6295552LL; // float4 units: mem 2097152 + feat 4194304 + tmem 4096

__device__ __forceinline__ float sgnf(float x) {
    return (x > 0.f) ? 1.f : ((x < 0.f) ? -1.f : 0.f);
}

__device__ __forceinline__ float wave_reduce(float v) {
#pragma unroll
    for (int o = 32; o > 0; o >>= 1) v += __shfl_down(v, o, 64);
    return v; // lane 0 holds sum
}

// ------------- background copy: slice [cbase, cbase+ccnt) of U_TOTAL -------------
__device__ __forceinline__ void copy_role(int rb, int cbase, int ccnt,
    const int* __restrict__ tptr, const int* __restrict__ dsptr,
    const float* __restrict__ x, const float* __restrict__ z,
    const float* __restrict__ memory, const int* __restrict__ t_memory,
    const float* __restrict__ feat_memory, float* __restrict__ out)
{
    const int dsv = *dsptr;
    const int tt  = *tptr;
    const int nthr = NCOPY * 256;
    for (int q = rb * 256 + (int)threadIdx.x; q * 4 < ccnt; q += nthr) {
#pragma unroll
        for (int w = 0; w < 4; ++w) {
            int rel = q * 4 + w;
            if (rel >= ccnt) break;
            int u = cbase + rel;
            if (u < 2097152) {               // memory (row ds <- z)
                int row = u >> 7;
                float4 v = (row == dsv) ? ((const float4*)z)[u & 127]
                                        : ((const float4*)memory)[u];
                ((float4*)(out + O_MEM))[u] = v;
            } else if (u < 6291456) {        // feat_memory (row ds <- x)
                int f = u - 2097152;
                int row = f >> 8;
                float4 v = (row == dsv) ? ((const float4*)x)[f & 255]
                                        : ((const float4*)feat_memory)[f];
                ((float4*)(out + O_FEAT))[f] = v;
            } else {                          // t_memory -> float (row ds <- t)
                int f = u - 6291456;
                int4 iv = ((const int4*)t_memory)[f];
                int e = f * 4;
                float* o = out + O_TMEM + e;
                o[0] = (e + 0 == dsv) ? (float)tt : (float)iv.x;
                o[1] = (e + 1 == dsv) ? (float)tt : (float)iv.y;
                o[2] = (e + 2 == dsv) ? (float)tt : (float)iv.z;
                o[3] = (e + 3 == dsv) ? (float)tt : (float)iv.w;
            }
        }
    }
}

#define COPY_ARGS const int* __restrict__ tptr, const int* __restrict__ dsptr,            \
                  const float* __restrict__ x, const float* __restrict__ z,               \
                  const float* __restrict__ memory, const int* __restrict__ t_memory,     \
                  const float* __restrict__ feat_memory, int cbase, int ccnt
#define COPY_PASS tptr, dsptr, x, z, memory, t_memory, feat_memory

// ======== K1: fused cat + split-K matmul partials. block=(i, s-chunk) ========
__global__ __launch_bounds__(256) void k_fwd_ab(int b, const int* __restrict__ ts,
    const float* __restrict__ cf,
    const float* __restrict__ are_src, const float* __restrict__ aim_src,
    const float* __restrict__ fq_src, const float* __restrict__ fm_in,
    const float* __restrict__ rp_src,
    float* __restrict__ out, float* __restrict__ ws, COPY_ARGS)
{
    const int bb = blockIdx.x, tid = threadIdx.x;
    if (bb >= 256) { copy_role(bb - 256, cbase, ccnt, COPY_PASS, out); return; }
    const int i = bb >> 4, s = bb & 15;
    __shared__ float c_l[32], s_l[32], cat[96];
    const int dsv = *dsptr;
    const int bi = ts[b * BATCHSZ + i];
    if (tid < 32) {
        float f  = fq_src[tid];
        float th = tanhf(f);
        float u  = cf[tid] + 2.f * th;
        float sg = 1.f / (1.f + expf(-u));
        float fr = 0.5f * sg;
        float tb = (bi == dsv) ? (float)(*tptr) : (float)t_memory[bi];
        float ph = TWO_PI * tb * fr;
        float cv = cosf(ph), sv = sinf(ph);
        c_l[tid] = cv; s_l[tid] = sv;
        if (s == 0) {
            ws[W_C + i*32 + tid] = cv; ws[W_S + i*32 + tid] = sv;
            if (tid == 0) ws[W_TB + i] = tb;
        }
    }
    if (bb == 0) {  // per-batch accumulator init
        if (tid == 64) ws[W_ANORM + b] = 0.f;
        if (tid == 65) ws[W_RNORM + b] = 0.f;
        if (tid == 66 && b == 0) ws[W_LR] = (float)pow(0.977, (double)(dsv + 1));
        if (tid >= 96 && tid < 128) ws[W_GFR + b*32 + tid - 96] = 0.f;
    }
    __syncthreads();
    if (tid < 96) {                     // compute this block's 96-elem cat slice
        int p = s * 96 + tid;
        float cv;
        if (p < NF) {
            const float nn = (float)(dsv + 1), dd = (float)(dsv + 2);
            float fmv = (fm_in[p] * nn + x[p]) / dd;
            float xv  = (bi == dsv) ? x[p] : feat_memory[bi*NF + p];
            cv = xv - fmv;
            ws[W_CATX + i*NF + p] = cv;
        } else {
            int q = p - NF;
            float acc = 0.f;
#pragma unroll
            for (int k = 0; k < 32; ++k)
                acc += c_l[k] * are_src[k*NT + q] - s_l[k] * aim_src[k*NT + q];
            cv = acc * INV_SQRT_NF;     // z_ - bias
            ws[W_CATZ + i*NT + q] = cv;
        }
        cat[tid] = cv;
    }
    __syncthreads();
    const int j = tid;
    const float* rpb = rp_src + (size_t)s * 96 * NT;
    float a0 = 0.f, a1 = 0.f, b0 = 0.f, b1 = 0.f;
#pragma unroll 8
    for (int p = 0; p < 96; p += 2) {
        float c0 = cat[p], c1 = cat[p + 1];
        a0 += c0 * rpb[p*NT + j];
        a1 += c0 * rpb[p*NT + j + 256];
        b0 += c1 * rpb[(p+1)*NT + j];
        b1 += c1 * rpb[(p+1)*NT + j + 256];
    }
    ws[W_RPART + s*8192 + i*NT + j]       = a0 + b0;
    ws[W_RPART + s*8192 + i*NT + j + 256] = a1 + b1;
}

// ======== K2: epilogue — g_r + FULL G, parallel. block=(i, j-group of 8) ========
__global__ __launch_bounds__(256) void k_eplg3(int b, const int* __restrict__ ts,
    const float* __restrict__ bias_in, const float* __restrict__ fm_in,
    const float* __restrict__ rp_src,
    float* __restrict__ out, float* __restrict__ ws, COPY_ARGS)
{
    const int bb = blockIdx.x, tid = threadIdx.x;
    if (bb >= 1024) { copy_role(bb - 1024, cbase, ccnt, COPY_PASS, out); return; }
    const int i = bb >> 6, jg = bb & 63;
    __shared__ float g_sh[NT], d_sh[NT];
    const int dsv = *dsptr;
    const int bi = ts[b * BATCHSZ + i];
    const float nn = (float)(dsv + 1), dd = (float)(dsv + 2);
#pragma unroll
    for (int ll = 0; ll < 2; ++ll) {
        int l = tid + ll * 256;
        float r = 0.f;
#pragma unroll
        for (int s = 0; s < 16; ++s) r += ws[W_RPART + s*8192 + i*NT + l];
        float bn = (bias_in[l] * nn + z[l]) / dd;
        float zj = ws[W_CATZ + i*NT + l] + bn;
        float zb = (bi == dsv) ? z[l] : memory[bi*NT + l];
        float s1 = sgnf(zj - zb);
        float ar = fabsf(r) + 1.f;
        float z2 = zj + r / ar;
        float g  = sgnf(z2 - zb) * (MM_LR / 16.f) / (ar * ar);
        g_sh[l] = g; d_sh[l] = s1 * (1.f / 16.f);
        if (jg == 0) {
            ws[W_GR + i*NT + l] = g;
            if (b == 0 && i == 0) out[O_BIAS + l] = bn;
        }
    }
    if (b == 0 && jg == 0 && i < 2) {   // fm_new (i=0,1 cover 1024)
#pragma unroll
        for (int ll = 0; ll < 2; ++ll) {
            int p = i * 512 + tid + ll * 256;
            out[O_FM + p] = (fm_in[p] * nn + x[p]) / dd;
        }
    }
    __syncthreads();
    const int w = tid >> 6, lane = tid & 63;
#pragma unroll
    for (int jj = 0; jj < 2; ++jj) {
        int j = jg * 8 + w * 2 + jj;
        const float* rrow = rp_src + (size_t)(NF + j) * NT;
        float acc = 0.f;
#pragma unroll
        for (int l = lane; l < NT; l += 64) acc += g_sh[l] * rrow[l];
        acc = wave_reduce(acc);
        if (lane == 0) ws[W_G + i*NT + j] = d_sh[j] + acc;
    }
}

// ======== K3: all norms — amp grads+anorm [0,64) | gfr [64,192) | rg+rnorm [192,3264) ========
__global__ __launch_bounds__(256) void k_norms(int b,
    const float* __restrict__ are_src, const float* __restrict__ aim_src,
    float* __restrict__ out, float* __restrict__ ws, COPY_ARGS)
{
    __shared__ float red[4];
    const int bb = blockIdx.x, tid = threadIdx.x;
    if (bb >= 3264) { copy_role(bb - 3264, cbase, ccnt, COPY_PASS, out); return; }
    if (bb < 64) {
        int e = bb*256 + tid;
        int k = e >> 9;
        float gre = 0.f, gim = 0.f;
#pragma unroll
        for (int i2 = 0; i2 < 16; ++i2) {
            float G = ws[W_G + i2*NT + (e & 511)];
            gre += G * ws[W_C + i2*32 + k];
            gim += G * ws[W_S + i2*32 + k];
        }
        float re = are_src[e], im = aim_src[e];
        float aa = sqrtf(re*re + im*im);
        float dec = AMP_DECAY / (2.f * aa * sqrtf(aa));
        float agr =  gre * INV_SQRT_NF + re * dec;
        float agi = -gim * INV_SQRT_NF + im * dec;
        ws[W_AGRE + e] = agr;
        ws[W_AGIM + e] = agi;
        float v = wave_reduce(agr*agr + agi*agi);
        if ((tid & 63) == 0) red[tid >> 6] = v;
        __syncthreads();
        if (tid == 0) atomicAdd(&ws[W_ANORM + b], red[0]+red[1]+red[2]+red[3]);
    } else if (bb < 192) {
        int wid = tid >> 6, lane = tid & 63;
        int pair = (bb - 64)*4 + wid;      // 512 = 16 i x 32 k
        int i = pair >> 5, k = pair & 31;
        float ck = ws[W_C + i*32 + k], sk = ws[W_S + i*32 + k];
        float acc = 0.f;
#pragma unroll
        for (int j = lane; j < NT; j += 64)
            acc += ws[W_G + i*NT + j] * (-sk * are_src[k*NT + j] - ck * aim_src[k*NT + j]);
        acc = wave_reduce(acc);
        if (lane == 0)
            atomicAdd(&ws[W_GFR + b*32 + k], acc * TWO_PI * ws[W_TB + i] * INV_SQRT_NF);
    } else {
        int e = (bb - 192)*256 + tid;
        int p = e >> 9, j = e & 511;
        float rg = 0.f;
#pragma unroll
        for (int i2 = 0; i2 < 16; ++i2) {
            float cat = (p < NF) ? ws[W_CATX + i2*NF + p]
                                 : ws[W_CATZ + i2*NT + (p - NF)];
            rg += cat * ws[W_GR + i2*NT + j];
        }
        float v = wave_reduce(rg * rg);
        if ((tid & 63) == 0) red[tid >> 6] = v;
        __syncthreads();
        if (tid == 0) atomicAdd(&ws[W_RNORM + b], red[0]+red[1]+red[2]+red[3]);
    }
}

// ======== K4: parameter updates ========
__global__ __launch_bounds__(256) void k_upd(int b, const float* __restrict__ cf,
    const float* __restrict__ are_src, const float* __restrict__ aim_src,
    const float* __restrict__ agr_src, const float* __restrict__ agi_src,
    const float* __restrict__ fq_src,  const float* __restrict__ fgr_src,
    const float* __restrict__ rp_src,  const float* __restrict__ rpg_src,
    float* __restrict__ out, float* __restrict__ ws, COPY_ARGS)
{
    const int bb = blockIdx.x, tid = threadIdx.x;
    if (bb >= 3137) { copy_role(bb - 3137, cbase, ccnt, COPY_PASS, out); return; }
    const float lr = ws[W_LR];
    if (bb < 64) {
        int e = bb*256 + tid;
        float anorm = sqrtf(ws[W_ANORM + b]) + 1.f;
        float mr = agr_src[e]*MOM + ws[W_AGRE + e]/anorm;
        out[O_AGR + e] = mr; out[O_ARE + e] = are_src[e] - mr*lr;
        float mi = agi_src[e]*MOM + ws[W_AGIM + e]/anorm;
        out[O_AGI + e] = mi; out[O_AIM + e] = aim_src[e] - mi*lr;
    } else if (bb == 64) {
        if (tid < 64) {
            float fg = 0.f, th = 0.f;
            if (tid < 32) {
                float f = fq_src[tid];
                th = tanhf(f);
                float u  = cf[tid] + 2.f*th;
                float sg = 1.f / (1.f + expf(-u));
                fg = ws[W_GFR + b*32 + tid] * sg*(1.f-sg)*(1.f-th*th);
            }
            float t2 = fg*fg;
#pragma unroll
            for (int o = 32; o > 0; o >>= 1) t2 += __shfl_down(t2, o, 64);
            float tot = __shfl(t2, 0, 64);
            if (tid < 32) {
                float fnorm = sqrtf(tot) + 1.f;
                float m = fgr_src[tid]*MOM + fg/fnorm;
                out[O_FGR + tid] = m;
                out[O_FREQ + tid] = fq_src[tid] - m*lr;
            }
        }
    } else {
        int e = (bb - 65)*256 + tid;
        int p = e >> 9, j = e & 511;
        float rg = 0.f;
#pragma unroll
        for (int i2 = 0; i2 < 16; ++i2) {
            float cat = (p < NF) ? ws[W_CATX + i2*NF + p]
                                 : ws[W_CATZ + i2*NT + (p - NF)];
            rg += cat * ws[W_GR + i2*NT + j];   // same order as k_norms -> identical fp
        }
        float rnorm = sqrtf(ws[W_RNORM + b]) + 1.f;
        float m = rpg_src[e]*MOM + rg/rnorm;
        out[O_RPG + e] = m; out[O_RP + e] = rp_src[e] - m*lr;
    }
}

extern "C" void kernel_launch(void* const* d_in, const int* in_sizes, int n_in,
                              void* d_out, int out_size, void* d_ws, size_t ws_size,
                              hipStream_t stream)
{
    const int*   t            = (const int*)d_in[0];
    const int*   dsp          = (const int*)d_in[1];
    const int*   ts           = (const int*)d_in[2];
    const float* x            = (const float*)d_in[3];
    const float* z            = (const float*)d_in[4];
    const float* memory       = (const float*)d_in[5];
    const int*   t_memory     = (const int*)d_in[6];
    const float* feat_memory  = (const float*)d_in[7];
    const float* amp_re       = (const float*)d_in[8];
    const float* amp_im       = (const float*)d_in[9];
    const float* freq         = (const float*)d_in[10];
    const float* cf           = (const float*)d_in[11];
    const float* res_proj     = (const float*)d_in[12];
    const float* feat_mean    = (const float*)d_in[13];
    const float* bias         = (const float*)d_in[14];
    const float* amp_grad_re  = (const float*)d_in[15];
    const float* amp_grad_im  = (const float*)d_in[16];
    const float* freq_grad    = (const float*)d_in[17];
    const float* res_proj_grad= (const float*)d_in[18];
    float* out = (float*)d_out;
    float* ws  = (float*)d_ws;

    const float* ARE[2] = { amp_re,        out + O_ARE };
    const float* AIM[2] = { amp_im,        out + O_AIM };
    const float* AGR[2] = { amp_grad_re,   out + O_AGR };
    const float* AGI[2] = { amp_grad_im,   out + O_AGI };
    const float* FQ [2] = { freq,          out + O_FREQ };
    const float* FGR[2] = { freq_grad,     out + O_FGR };
    const float* RP [2] = { res_proj,      out + O_RP };
    const float* RPG[2] = { res_proj_grad, out + O_RPG };

    // 8 equal copy slices (U_TOTAL = 8 * 786944)
    const int per = 786944;
    int base = 0;
    auto nxt = [&](int& cb, int& cc) { cb = base; cc = per; base += cc; };
    int cb, cc;
    for (int b = 0; b < 2; ++b) {
        nxt(cb, cc);
        k_fwd_ab<<<256 + NCOPY, 256, 0, stream>>>(b, ts, cf, ARE[b], AIM[b], FQ[b],
            feat_mean, RP[b], out, ws, t, dsp, x, z, memory, t_memory, feat_memory, cb, cc);
        nxt(cb, cc);
        k_eplg3<<<1024 + NCOPY, 256, 0, stream>>>(b, ts, bias, feat_mean, RP[b], out, ws,
            t, dsp, x, z, memory, t_memory, feat_memory, cb, cc);
        nxt(cb, cc);
        k_norms<<<3264 + NCOPY, 256, 0, stream>>>(b, ARE[b], AIM[b], out, ws,
            t, dsp, x, z, memory, t_memory, feat_memory, cb, cc);
        nxt(cb, cc);
        k_upd<<<3137 + NCOPY, 256, 0, stream>>>(b, cf, ARE[b], AIM[b], AGR[b], AGI[b],
            FQ[b], FGR[b], RP[b], RPG[b], out, ws,
            t, dsp, x, z, memory, t_memory, feat_memory, cb, cc);
    }
}